// Round 1
// baseline (66.323 us; speedup 1.0000x reference)
//
#include <hip/hip_runtime.h>

#define ORDER 8
#define FDIM 4096
#define NROWS 8192
#define THREADS 256
#define RPB 4            // rows of x per block
#define F4T 4            // float4s per thread per row: 4096/4/256
#define F4DIM (FDIM/4)   // 1024 float4s per row

// ---------------------------------------------------------------------------
// Prep: reparameterize v, d, bias; normalize v rows.
// blocks 0..7  -> vn row b
// block  8     -> d scale vector
// block  9     -> bias vector
// ---------------------------------------------------------------------------
__global__ __launch_bounds__(THREADS) void obd_prep(
    const float* __restrict__ v_mean, const float* __restrict__ v_logvar,
    const float* __restrict__ eps_v,
    const float* __restrict__ d_mean, const float* __restrict__ d_logvar,
    const float* __restrict__ eps_d,
    const float* __restrict__ b_mean, const float* __restrict__ b_logvar,
    const float* __restrict__ eps_b,
    float* __restrict__ vn, float* __restrict__ dsc, float* __restrict__ bias)
{
    const int b = blockIdx.x;
    const int t = threadIdx.x;
    __shared__ float red[THREADS / 64];

    if (b < ORDER) {
        const float4* vm = (const float4*)(v_mean   + (size_t)b * FDIM);
        const float4* vl = (const float4*)(v_logvar + (size_t)b * FDIM);
        const float4* ev = (const float4*)(eps_v    + (size_t)b * FDIM);
        float4 val[F4T];
        float ss = 0.f;
        #pragma unroll
        for (int k = 0; k < F4T; ++k) {
            const int idx = t + k * THREADS;
            float4 m = vm[idx], l = vl[idx], e = ev[idx];
            float4 v;
            v.x = fmaf(expf(0.5f * l.x), e.x, m.x);
            v.y = fmaf(expf(0.5f * l.y), e.y, m.y);
            v.z = fmaf(expf(0.5f * l.z), e.z, m.z);
            v.w = fmaf(expf(0.5f * l.w), e.w, m.w);
            val[k] = v;
            ss += v.x * v.x + v.y * v.y + v.z * v.z + v.w * v.w;
        }
        #pragma unroll
        for (int off = 32; off; off >>= 1) ss += __shfl_down(ss, off);
        const int wave = t >> 6, lane = t & 63;
        if (lane == 0) red[wave] = ss;
        __syncthreads();
        const float tot = red[0] + red[1] + red[2] + red[3];
        const float inv = 1.0f / sqrtf(tot);
        float4* vno = (float4*)(vn + (size_t)b * FDIM);
        #pragma unroll
        for (int k = 0; k < F4T; ++k) {
            const int idx = t + k * THREADS;
            float4 v = val[k];
            v.x *= inv; v.y *= inv; v.z *= inv; v.w *= inv;
            vno[idx] = v;
        }
    } else if (b == ORDER) {
        #pragma unroll
        for (int k = 0; k < 16; ++k) {
            const int idx = t + k * THREADS;
            dsc[idx] = fmaf(expf(0.5f * d_logvar[idx]), eps_d[idx], d_mean[idx]);
        }
    } else {
        #pragma unroll
        for (int k = 0; k < 16; ++k) {
            const int idx = t + k * THREADS;
            bias[idx] = fmaf(expf(0.5f * b_logvar[idx]), eps_b[idx], b_mean[idx]);
        }
    }
}

// ---------------------------------------------------------------------------
// Main: per block, 4 rows of x live in registers; apply 8 Householder
// reflections from the right (dot -> block reduce -> rank-1 update), then
// fused scale-by-d + bias epilogue. Memory-bound: x read once, out written
// once; vn/d/bias are L2-resident and amortized over 4 rows per load.
// ---------------------------------------------------------------------------
__global__ __launch_bounds__(THREADS) void obd_apply(
    const float* __restrict__ x, const float* __restrict__ vn,
    const float* __restrict__ dsc, const float* __restrict__ bias,
    float* __restrict__ out)
{
    const int t = threadIdx.x;
    const size_t row0 = (size_t)blockIdx.x * RPB;
    const float4* xv = (const float4*)x;
    float4* ov = (float4*)out;

    // Load 4 rows into registers (perfectly coalesced float4s).
    float4 r[RPB][F4T];
    #pragma unroll
    for (int rr = 0; rr < RPB; ++rr) {
        const size_t base = (row0 + rr) * F4DIM;
        #pragma unroll
        for (int k = 0; k < F4T; ++k)
            r[rr][k] = xv[base + t + k * THREADS];
    }

    __shared__ float4 red[ORDER][THREADS / 64];  // [reflection][wave] -> 4 row-dots
    const int wave = t >> 6, lane = t & 63;

    #pragma unroll
    for (int i = 0; i < ORDER; ++i) {
        const float4* vrow = (const float4*)(vn + (size_t)i * FDIM);
        float4 vc[F4T];
        float p[RPB] = {0.f, 0.f, 0.f, 0.f};
        #pragma unroll
        for (int k = 0; k < F4T; ++k) {
            vc[k] = vrow[t + k * THREADS];
            #pragma unroll
            for (int rr = 0; rr < RPB; ++rr) {
                p[rr] = fmaf(r[rr][k].x, vc[k].x, p[rr]);
                p[rr] = fmaf(r[rr][k].y, vc[k].y, p[rr]);
                p[rr] = fmaf(r[rr][k].z, vc[k].z, p[rr]);
                p[rr] = fmaf(r[rr][k].w, vc[k].w, p[rr]);
            }
        }
        // 64-lane shuffle reduce (4 independent values in flight)
        #pragma unroll
        for (int off = 32; off; off >>= 1) {
            #pragma unroll
            for (int rr = 0; rr < RPB; ++rr)
                p[rr] += __shfl_down(p[rr], off);
        }
        if (lane == 0) red[i][wave] = make_float4(p[0], p[1], p[2], p[3]);
        __syncthreads();   // one barrier per reflection; per-reflection slots avoid WAR
        const float4 a0 = red[i][0], a1 = red[i][1], a2 = red[i][2], a3 = red[i][3];
        const float dot[RPB] = { a0.x + a1.x + a2.x + a3.x,
                                 a0.y + a1.y + a2.y + a3.y,
                                 a0.z + a1.z + a2.z + a3.z,
                                 a0.w + a1.w + a2.w + a3.w };
        #pragma unroll
        for (int rr = 0; rr < RPB; ++rr) {
            const float c = -2.0f * dot[rr];
            #pragma unroll
            for (int k = 0; k < F4T; ++k) {
                r[rr][k].x = fmaf(c, vc[k].x, r[rr][k].x);
                r[rr][k].y = fmaf(c, vc[k].y, r[rr][k].y);
                r[rr][k].z = fmaf(c, vc[k].z, r[rr][k].z);
                r[rr][k].w = fmaf(c, vc[k].w, r[rr][k].w);
            }
        }
    }

    // Epilogue: out = y * d + bias
    #pragma unroll
    for (int k = 0; k < F4T; ++k) {
        const int idx = t + k * THREADS;
        const float4 dd = ((const float4*)dsc)[idx];
        const float4 bb = ((const float4*)bias)[idx];
        #pragma unroll
        for (int rr = 0; rr < RPB; ++rr) {
            float4 o;
            o.x = fmaf(r[rr][k].x, dd.x, bb.x);
            o.y = fmaf(r[rr][k].y, dd.y, bb.y);
            o.z = fmaf(r[rr][k].z, dd.z, bb.z);
            o.w = fmaf(r[rr][k].w, dd.w, bb.w);
            ov[(row0 + rr) * F4DIM + idx] = o;
        }
    }
}

extern "C" void kernel_launch(void* const* d_in, const int* in_sizes, int n_in,
                              void* d_out, int out_size, void* d_ws, size_t ws_size,
                              hipStream_t stream) {
    const float* x        = (const float*)d_in[0];
    const float* v_mean   = (const float*)d_in[1];
    const float* v_logvar = (const float*)d_in[2];
    const float* d_mean   = (const float*)d_in[3];
    const float* d_logvar = (const float*)d_in[4];
    const float* b_mean   = (const float*)d_in[5];
    const float* b_logvar = (const float*)d_in[6];
    const float* eps_v    = (const float*)d_in[7];
    const float* eps_d    = (const float*)d_in[8];
    const float* eps_b    = (const float*)d_in[9];

    float* ws   = (float*)d_ws;
    float* vn   = ws;                          // 8*4096 floats
    float* dsc  = ws + ORDER * FDIM;           // 4096 floats
    float* bias = ws + ORDER * FDIM + FDIM;    // 4096 floats

    obd_prep<<<ORDER + 2, THREADS, 0, stream>>>(
        v_mean, v_logvar, eps_v, d_mean, d_logvar, eps_d,
        b_mean, b_logvar, eps_b, vn, dsc, bias);
    obd_apply<<<NROWS / RPB, THREADS, 0, stream>>>(
        x, vn, dsc, bias, (float*)d_out);
}